// Round 1
// baseline (62.415 us; speedup 1.0000x reference)
//
#include <hip/hip_runtime.h>

// Problem constants (from reference)
#define BB   1024
#define PP   32
#define NNEG 64
#define NBH  32
#define NNH  32
#define DD   64

static constexpr float W1c = 1.0f;
static constexpr float W2c = 0.1f;
static constexpr float W3c = 1.0f;

// ---------------------------------------------------------------------------
// Mask layout detection: masks are jnp bool arrays; the harness may ship them
// as 1-byte bool (flag=1), int32 0/1 (flag=0), or float32 0/1.0 (flag=2).
// Scan the first 8192 words (32KB) of pos_mask — safe under every layout
// (byte layout buffer is exactly 32768 bytes).
//   int32 layout : words in {0,1}
//   f32   layout : words in {0, 0x3f800000}
//   byte  layout : packed bool bytes; prefix masks guarantee some word with a
//                  nonzero byte in positions 1..3 (lens>=2 w.p. 31/32 per row)
// ---------------------------------------------------------------------------
__global__ void detect_mask_layout(const unsigned int* __restrict__ mask_words,
                                   int* __restrict__ flag_out) {
    __shared__ int sh_f32, sh_byte;
    if (threadIdx.x == 0) { sh_f32 = 0; sh_byte = 0; }
    __syncthreads();
    int f32hit = 0, bytehit = 0;
    for (int i = threadIdx.x; i < 8192; i += blockDim.x) {
        unsigned int v = mask_words[i];
        if (v == 0x3f800000u) f32hit = 1;
        else if (v & 0xFFFFFF00u) bytehit = 1;
    }
    if (f32hit)  atomicOr(&sh_f32, 1);
    if (bytehit) atomicOr(&sh_byte, 1);
    __syncthreads();
    if (threadIdx.x == 0)
        *flag_out = sh_f32 ? 2 : (sh_byte ? 1 : 0);
}

__device__ __forceinline__ float parse_mask(const void* p, int flag, int j) {
    if (flag == 1) return ((const unsigned char*)p)[j] ? 1.0f : 0.0f;
    if (flag == 2) return (((const float*)p)[j] != 0.0f) ? 1.0f : 0.0f;
    return ((const int*)p)[j] ? 1.0f : 0.0f;
}

// ---------------------------------------------------------------------------
// Main loss kernel: one block per batch element b, 256 threads (4 waves).
// ---------------------------------------------------------------------------
__global__ __launch_bounds__(256) void loss_kernel(
    const float* __restrict__ u2e, const float* __restrict__ v2e,
    const float* __restrict__ margin_uv, const float* __restrict__ margin_vv,
    const float* __restrict__ margin_uu,
    const int* __restrict__ train_u, const int* __restrict__ pos_idx,
    const int* __restrict__ neg_idx, const int* __restrict__ nb_idx,
    const int* __restrict__ nn_idx,
    const void* __restrict__ pos_mask, const void* __restrict__ neg_mask,
    const void* __restrict__ nb_mask, const void* __restrict__ nn_mask,
    const int* __restrict__ flag_p, float* __restrict__ ws) {

    const int b = blockIdx.x;
    const int t = threadIdx.x;
    const int lane = t & 63;
    const int w = t >> 6;
    const int flag = *flag_p;

    __shared__ float u_s[DD];
    __shared__ float p_lds[PP][DD + 1];    // stride 65: bank-conflict-free dots
    __shared__ float n_lds[NNEG][DD + 1];
    __shared__ float d1[PP], p2[PP], d2[NNEG], n2[NNEG], d1s[NBH], d2s[NNH];
    __shared__ float mv[PP], pmf[PP], nmf[NNEG], nbmf[NBH], nnmf[NNH];
    __shared__ int   pos_i[PP], neg_i[NNEG], nb_i[NBH], nn_i[NNH];
    __shared__ float sc[2];                // m_u, m_s
    __shared__ float red[4][3];

    const int tu = train_u[b];

    // Phase 0: indices, margins, masks, u row
    if (t < DD) u_s[t] = u2e[(size_t)tu * DD + t];
    if (t < PP) {
        int pi = pos_idx[b * PP + t];
        pos_i[t] = pi;
        mv[t]    = margin_vv[pi];
        pmf[t]   = parse_mask(pos_mask, flag, b * PP + t);
    } else if (t < PP + NNEG) {
        int j = t - PP;
        neg_i[j] = neg_idx[b * NNEG + j];
        nmf[j]   = parse_mask(neg_mask, flag, b * NNEG + j);
    } else if (t < PP + NNEG + NBH) {
        int j = t - PP - NNEG;
        nb_i[j]  = nb_idx[b * NBH + j];
        nbmf[j]  = parse_mask(nb_mask, flag, b * NBH + j);
    } else if (t < PP + NNEG + NBH + NNH) {
        int j = t - PP - NNEG - NBH;
        nn_i[j]  = nn_idx[b * NNH + j];
        nnmf[j]  = parse_mask(nn_mask, flag, b * NNH + j);
    }
    if (t == 0) { sc[0] = margin_uv[tu]; sc[1] = margin_uu[tu]; }
    __syncthreads();

    // Phase 1: gather rows, stage p/n in LDS, wave-reduce distances & norms.
    // 160 rows total: [0,32) p, [32,96) n, [96,128) nb, [128,160) nn.
    const float ue = u_s[lane];
    for (int r = w; r < 160; r += 4) {
        if (r < PP) {
            float e = v2e[(size_t)pos_i[r] * DD + lane];
            p_lds[r][lane] = e;
            float df = e - ue;
            float sd = df * df, sq = e * e;
            for (int m = 1; m < 64; m <<= 1) {
                sd += __shfl_xor(sd, m);
                sq += __shfl_xor(sq, m);
            }
            if (lane == 0) { d1[r] = sd; p2[r] = sq; }
        } else if (r < PP + NNEG) {
            int k = r - PP;
            float e = v2e[(size_t)neg_i[k] * DD + lane];
            n_lds[k][lane] = e;
            float df = e - ue;
            float sd = df * df, sq = e * e;
            for (int m = 1; m < 64; m <<= 1) {
                sd += __shfl_xor(sd, m);
                sq += __shfl_xor(sq, m);
            }
            if (lane == 0) { d2[k] = sd; n2[k] = sq; }
        } else if (r < PP + NNEG + NBH) {
            int i = r - PP - NNEG;
            float e = u2e[(size_t)nb_i[i] * DD + lane];
            float df = e - ue;
            float sd = df * df;
            for (int m = 1; m < 64; m <<= 1) sd += __shfl_xor(sd, m);
            if (lane == 0) d1s[i] = sd;
        } else {
            int i = r - PP - NNEG - NBH;
            float e = u2e[(size_t)nn_i[i] * DD + lane];
            float df = e - ue;
            float sd = df * df;
            for (int m = 1; m < 64; m <<= 1) sd += __shfl_xor(sd, m);
            if (lane == 0) d2s[i] = sd;
        }
    }
    __syncthreads();

    // Phase 2: hinge sums.
    const float m_u = sc[0], m_s = sc[1];
    float acc = 0.0f;
    {
        const int i  = t >> 3;        // 0..31
        const int kb = t & 7;
        const float d1i = d1[i], p2i = p2[i], pmi = pmf[i];
        #pragma unroll
        for (int q = 0; q < 8; ++q) {
            const int k = kb + 8 * q; // 0..63
            float pn = 0.0f;
            #pragma unroll
            for (int d = 0; d < DD; ++d)
                pn = fmaf(p_lds[i][d], n_lds[k][d], pn);
            const float cc = d1i - (p2i + n2[k] - 2.0f * pn);
            float inner = 0.0f;
            #pragma unroll
            for (int j = 0; j < PP; ++j)
                inner += pmf[j] * fmaxf(mv[j] + cc, 0.0f);
            const float mk = pmi * nmf[k];
            acc += W1c * mk * inner;                              // vv
            acc += mk * fmaxf(m_u + d1i - d2[k], 0.0f);           // uv
        }
    }
    for (int pid = t; pid < NBH * NNH; pid += 256) {              // uu
        int i = pid >> 5, k = pid & 31;
        acc += W3c * nbmf[i] * nnmf[k] * fmaxf(m_s + d1s[i] - d2s[k], 0.0f);
    }

    float a2 = (t < PP) ? mv[t] * pmf[t] : 0.0f;                  // sum m_v*pm
    float a3 = (t < PP) ? pmf[t] : 0.0f;                          // sum pm
    for (int m = 1; m < 64; m <<= 1) {
        acc += __shfl_xor(acc, m);
        a2  += __shfl_xor(a2, m);
        a3  += __shfl_xor(a3, m);
    }
    if (lane == 0) { red[w][0] = acc; red[w][1] = a2; red[w][2] = a3; }
    __syncthreads();
    if (t == 0) {
        float S0 = 0, S2 = 0, S3 = 0;
        for (int i = 0; i < 4; ++i) { S0 += red[i][0]; S2 += red[i][1]; S3 += red[i][2]; }
        ws[0 * BB + b] = S0;
        ws[1 * BB + b] = sc[0];
        ws[2 * BB + b] = S2;
        ws[3 * BB + b] = S3;
        ws[4 * BB + b] = sc[1];
    }
}

// ---------------------------------------------------------------------------
// Finalize: deterministic tree reduction of the 5 per-block partial arrays.
// ---------------------------------------------------------------------------
__global__ __launch_bounds__(256) void finalize_kernel(const float* __restrict__ ws,
                                                       float* __restrict__ out) {
    __shared__ float red[4][5];
    const int t = threadIdx.x, lane = t & 63, w = t >> 6;
    float s[5] = {0, 0, 0, 0, 0};
    for (int i = t; i < BB; i += 256)
        for (int a = 0; a < 5; ++a) s[a] += ws[a * BB + i];
    for (int m = 1; m < 64; m <<= 1)
        for (int a = 0; a < 5; ++a) s[a] += __shfl_xor(s[a], m);
    if (lane == 0)
        for (int a = 0; a < 5; ++a) red[w][a] = s[a];
    __syncthreads();
    if (t == 0) {
        float S[5];
        for (int a = 0; a < 5; ++a) {
            S[a] = 0;
            for (int i = 0; i < 4; ++i) S[a] += red[i][a];
        }
        float loss_am = S[1] / (float)BB + S[2] / S[3] + S[4] / (float)BB;
        out[0] = S[0] + W2c * loss_am;
    }
}

extern "C" void kernel_launch(void* const* d_in, const int* in_sizes, int n_in,
                              void* d_out, int out_size, void* d_ws, size_t ws_size,
                              hipStream_t stream) {
    const float* u2e       = (const float*)d_in[0];
    const float* v2e       = (const float*)d_in[1];
    const float* margin_uv = (const float*)d_in[2];
    const float* margin_vv = (const float*)d_in[3];
    const float* margin_uu = (const float*)d_in[4];
    const int*   train_u   = (const int*)d_in[5];
    const int*   pos_idx   = (const int*)d_in[6];
    const int*   neg_idx   = (const int*)d_in[7];
    const int*   nb_idx    = (const int*)d_in[8];
    const int*   nn_idx    = (const int*)d_in[9];
    const void*  pos_mask  = d_in[10];
    const void*  neg_mask  = d_in[11];
    const void*  nb_mask   = d_in[12];
    const void*  nn_mask   = d_in[13];

    float* ws      = (float*)d_ws;
    int*   flag_p  = (int*)(ws + 5 * BB);
    float* out     = (float*)d_out;

    detect_mask_layout<<<1, 256, 0, stream>>>((const unsigned int*)pos_mask, flag_p);
    loss_kernel<<<BB, 256, 0, stream>>>(u2e, v2e, margin_uv, margin_vv, margin_uu,
                                        train_u, pos_idx, neg_idx, nb_idx, nn_idx,
                                        pos_mask, neg_mask, nb_mask, nn_mask,
                                        flag_p, ws);
    finalize_kernel<<<1, 256, 0, stream>>>(ws, out);
}